// Round 11
// baseline (93.946 us; speedup 1.0000x reference)
//
#include <hip/hip_runtime.h>
#include <math.h>

#define B_ 4096
#define T_ 64
#define E_ 256
#define H_ 64
#define V_ 32000
#define THREADS 1024

typedef __attribute__((ext_vector_type(8))) short bf16x8;
typedef __attribute__((ext_vector_type(4))) float f32x4;
typedef __attribute__((ext_vector_type(4))) unsigned int u32x4;

__device__ __forceinline__ short f2bf(float x) {
    unsigned u = __float_as_uint(x);
    return (short)((u + 0x7FFFu + ((u >> 16) & 1u)) >> 16);
}
__device__ __forceinline__ unsigned cvt_pk_bf16(float lo, float hi) {
    unsigned r;
    asm("v_cvt_pk_bf16_f32 %0, %1, %2" : "=v"(r) : "v"(lo), "v"(hi));
    return r;
}
__device__ __forceinline__ float exp2_raw(float x) {
    float r; asm("v_exp_f32 %0, %1" : "=v"(r) : "v"(x)); return r;
}
__device__ __forceinline__ float rcp_raw(float x) {
    float r; asm("v_rcp_f32 %0, %1" : "=v"(r) : "v"(x)); return r;
}
#define LOG2E 1.442695041f

__device__ __forceinline__ void gld16(const void* g, void* l) {
    __builtin_amdgcn_global_load_lds(
        (const __attribute__((address_space(1))) void*)g,
        (__attribute__((address_space(3))) void*)l, 16, 0, 0);
}

// ---------------------------------------------------------------------------
// Prep (wih_frag layout identical to R4-R10, verified):
//  wih_frag[((vv*2+tl)*8 + kc)*512 + lane*8 + jj]:
//    gate g = tl*128 + (lane&1)*64 + vv*8 + ((lane&15)>>1)
//    k      = kc*32 + (lane>>4)*8 + jj
//  whh_g: bf16 [g][k] row-major;  bias_f = b_ih + b_hh
//  emb_bf: whole table bf16 (RNE) for global_load_lds staging.
// ---------------------------------------------------------------------------
__global__ void prep_kernel(const float* __restrict__ W_ih,
                            const float* __restrict__ W_hh,
                            const float* __restrict__ b_ih,
                            const float* __restrict__ b_hh,
                            const float* __restrict__ emb_table,
                            short* __restrict__ wih_frag,
                            short* __restrict__ whh_g,
                            float* __restrict__ bias_f,
                            short* __restrict__ emb_bf,
                            int tabN) {
    int tid = blockIdx.x * blockDim.x + threadIdx.x;
    int stride = gridDim.x * blockDim.x;
    for (int i = tid; i < 65536; i += stride) {
        int jj = i & 7;
        int l  = (i >> 3) & 63;
        int kc = (i >> 9) & 7;
        int tl = (i >> 12) & 1;
        int vv = i >> 13;
        int uu = (l & 15) >> 1, pp = l & 1;
        int g = tl * 128 + pp * 64 + vv * 8 + uu;
        int k = kc * 32 + (l >> 4) * 8 + jj;
        wih_frag[i] = f2bf(W_ih[g * E_ + k]);
    }
    for (int i = tid; i < 256 * 64; i += stride) whh_g[i] = f2bf(W_hh[i]);
    for (int i = tid; i < 256; i += stride) bias_f[i] = b_ih[i] + b_hh[i];
    for (int i = tid; i < (tabN >> 2); i += stride) {
        float4 v = ((const float4*)emb_table)[i];
        uint2 w;
        w.x = cvt_pk_bf16(v.x, v.y);
        w.y = cvt_pk_bf16(v.z, v.w);
        ((uint2*)emb_bf)[i] = w;
    }
}

// ---------------------------------------------------------------------------
// R10 structure + split-K accumulators + counted-vmcnt barriers.
// grid 256 (1 block/CU), 1024 threads = 16 waves, pinned 4 waves/EU.
//  waves 0-7  (compute): wave w owns vv=w. W_ih/W_hh register-resident.
//    Accumulation uses 4 INDEPENDENT chains (a0: i/f kc0-3 + hv0; a1: i/f
//    kc4-7 + hv1; b0/b1 same for g/o) merged with 8 VALU adds at gate entry
//    -> MFMA dep-chain depth 5 instead of 10 (R10's exposed-latency fix).
//  waves 8-15 (stage): wave 8+s stages chunk kc=s of emb(t+3) via ONE
//    global_load_lds dwordx4 (bf16 table, distance-3 prefetch, 4-ring).
// In-loop barrier: s_waitcnt vmcnt(1) lgkmcnt(0); s_barrier  -- the newest
// stage load stays in flight across the barrier (oldest must retire: its
// buffer is read two steps later).
// Fragment LDS layout (zero-conflict): chunk (kc,lane) at kc*1024B + lane*16B.
// ---------------------------------------------------------------------------
template <int TAB>
__global__ __attribute__((amdgpu_flat_work_group_size(THREADS, THREADS),
                          amdgpu_waves_per_eu(4, 4)))
void lstm_f(const int* __restrict__ x,
            const float* __restrict__ embf,
            const short* __restrict__ embb,
            const short* __restrict__ wih_frag,
            const short* __restrict__ whh_g,
            const float* __restrict__ bias_f,
            float* __restrict__ out) {
    __shared__ __align__(16) short s_ef[4][4096];   // 4-ring emb, 8 KB each
    __shared__ __align__(16) short s_hf[2][1024];   // 2-ring h, 2 KB each
    __shared__ int s_idx[1024];                     // [t][m]

    const int tid  = threadIdx.x;
    const int lane = tid & 63;
    const int wave = tid >> 6;
    const int r0   = blockIdx.x * 16;

    s_idx[(tid & 63) * 16 + (tid >> 6)] = x[(r0 + (tid >> 6)) * T_ + (tid & 63)];
    ((int*)s_hf)[tid] = 0;

    const int p  = lane & 1;
    const int c4 = lane >> 4;
    const int u  = (lane & 15) >> 1;
    const float scl2 = p ? 1.0f : 2.0f;
    const float offB = p ? 0.0f : -1.0f;
    const float enB  = -LOG2E * scl2;
    const int m0 = c4 * 4 + p * 2;

    // ---- compute-wave setup ----
    bf16x8 wA[8], wB[8], qA0, qA1, qB0, qB1;
    float bA = 0.f, bB = 0.f;
    int hw_s = 0;
    if (wave < 8) {
        const short* wp = wih_frag + wave * 8192 + lane * 8;
        #pragma unroll
        for (int kc = 0; kc < 8; ++kc) {
            wA[kc] = *(const bf16x8*)(wp + kc * 512);
            wB[kc] = *(const bf16x8*)(wp + 4096 + kc * 512);
        }
        const int gA = p * 64 + wave * 8 + u;
        const short* qp = whh_g + gA * 64 + c4 * 8;
        qA0 = *(const bf16x8*)(qp);
        qA1 = *(const bf16x8*)(qp + 32);
        qB0 = *(const bf16x8*)(qp + 8192);
        qB1 = *(const bf16x8*)(qp + 8192 + 32);
        bA = bias_f[gA];
        bB = bias_f[gA + 128];
        hw_s = (wave >> 2) * 512 + (wave & 3) * 128
             + ((u & 1) ? (m0 + 1) * 8 + (u - 1) : m0 * 8 + u);
    }

    // ---- stage-wave mapping: wave 8+s owns chunk kc=s ----
    const int m16   = lane & 15;
    const int sbase = (wave - 8) * 512 + lane * 8;                 // shorts
    const int skoff = (wave - 8) * 32 + (lane >> 4) * 8;           // emb col

    __syncthreads();   // s_idx, h=0 visible

    if (wave >= 8) {
        // prologue: stage t=0,1,2 (0,1 must complete; 2 may stay in flight)
        #pragma unroll
        for (int tt = 0; tt < 3; ++tt) {
            int tok = s_idx[tt * 16 + m16];
            if (TAB) {
                gld16(embb + (size_t)tok * E_ + skoff,
                      &s_ef[tt][(wave - 8) * 512]);
            } else {
                const float* pr = embf + (size_t)tok * E_ + skoff;
                float4 f0 = *(const float4*)pr;
                float4 f1 = *(const float4*)(pr + 4);
                u32x4 w;
                w[0] = cvt_pk_bf16(f0.x, f0.y);
                w[1] = cvt_pk_bf16(f0.z, f0.w);
                w[2] = cvt_pk_bf16(f1.x, f1.y);
                w[3] = cvt_pk_bf16(f1.z, f1.w);
                *(u32x4*)(&s_ef[tt][0] + sbase) = w;
            }
        }
    }
    if (TAB) {
        asm volatile("s_waitcnt vmcnt(1) lgkmcnt(0)" ::: "memory");
        __builtin_amdgcn_s_barrier();
        __builtin_amdgcn_sched_barrier(0);
    } else {
        __syncthreads();
    }

    // ---- compute prologue: pre-gates P(0) from buf0 (split-K) ----
    f32x4 a0, a1, b0, b1;
    if (wave < 8) {
        a0 = (f32x4){bA, bA, bA, bA};
        b0 = (f32x4){bB, bB, bB, bB};
        a1 = (f32x4){0.f, 0.f, 0.f, 0.f};
        b1 = (f32x4){0.f, 0.f, 0.f, 0.f};
        const short* eb = &s_ef[0][0] + lane * 8;
        #pragma unroll
        for (int kc = 0; kc < 4; ++kc) {
            bf16x8 av = *(const bf16x8*)(eb + kc * 512);
            bf16x8 aw = *(const bf16x8*)(eb + (kc + 4) * 512);
            a0 = __builtin_amdgcn_mfma_f32_16x16x32_bf16(av, wA[kc], a0, 0, 0, 0);
            b0 = __builtin_amdgcn_mfma_f32_16x16x32_bf16(av, wB[kc], b0, 0, 0, 0);
            a1 = __builtin_amdgcn_mfma_f32_16x16x32_bf16(aw, wA[kc + 4], a1, 0, 0, 0);
            b1 = __builtin_amdgcn_mfma_f32_16x16x32_bf16(aw, wB[kc + 4], b1, 0, 0, 0);
        }
    }

    float c0 = 0.f, c1 = 0.f, h0v = 0.f, h1v = 0.f;

    #pragma unroll 4
    for (int t = 0; t < T_; ++t) {
        if (wave < 8) {
            // ---- R: G(t) = preG + h(t-1)*Whh (independent chains) ----
            const short* hb = &s_hf[t & 1][0] + lane * 8;
            bf16x8 hv0 = *(const bf16x8*)(hb);
            bf16x8 hv1 = *(const bf16x8*)(hb + 512);
            a0 = __builtin_amdgcn_mfma_f32_16x16x32_bf16(hv0, qA0, a0, 0, 0, 0);
            a1 = __builtin_amdgcn_mfma_f32_16x16x32_bf16(hv1, qA1, a1, 0, 0, 0);
            b0 = __builtin_amdgcn_mfma_f32_16x16x32_bf16(hv0, qB0, b0, 0, 0, 0);
            b1 = __builtin_amdgcn_mfma_f32_16x16x32_bf16(hv1, qB1, b1, 0, 0, 0);

            // ---- gates (merge split-K; raw v_exp/v_rcp; parity interleave) ----
            float sA[4], Bv[4];
            #pragma unroll
            for (int q = 0; q < 4; ++q) {
                float gaq = a0[q] + a1[q];
                float gbq = b0[q] + b1[q];
                sA[q] = rcp_raw(1.0f + exp2_raw(-LOG2E * gaq));          // sigm(i)|sigm(f)
                Bv[q] = rcp_raw(1.0f + exp2_raw(enB * gbq)) * scl2 + offB; // tanh(g)|sigm(o)
            }
            float s1 = p ? sA[0] : sA[2] * Bv[2];
            float r1 = __shfl_xor(s1, 1);
            float s2 = p ? sA[1] : sA[3] * Bv[3];
            float r2 = __shfl_xor(s2, 1);
            float r3 = __shfl_xor(Bv[0], 1);
            float r4 = __shfl_xor(Bv[1], 1);
            float fc0 = p ? sA[2] : r1;
            float ic0 = p ? r1 : sA[0] * Bv[0];
            float oc0 = p ? Bv[2] : r3;
            float fc1 = p ? sA[3] : r2;
            float ic1 = p ? r2 : sA[1] * Bv[1];
            float oc1 = p ? Bv[3] : r4;
            c0 = fc0 * c0 + ic0;
            c1 = fc1 * c1 + ic1;
            h0v = oc0 * (1.0f - 2.0f * rcp_raw(1.0f + exp2_raw(2.0f * LOG2E * c0)));
            h1v = oc1 * (1.0f - 2.0f * rcp_raw(1.0f + exp2_raw(2.0f * LOG2E * c1)));

            // packed b32 h-write (column-pair via lane^2 exchange, cvt_pk)
            float snd = (u & 1) ? h0v : h1v;
            float rcv = __shfl_xor(snd, 2);
            unsigned hw = (u & 1) ? cvt_pk_bf16(rcv, h1v) : cvt_pk_bf16(h0v, rcv);
            *(unsigned*)(&s_hf[(t + 1) & 1][0] + hw_s) = hw;

            // ---- P: preG(t+1), 4 independent chains ----
            if (t < T_ - 1) {
                a0 = (f32x4){bA, bA, bA, bA};
                b0 = (f32x4){bB, bB, bB, bB};
                a1 = (f32x4){0.f, 0.f, 0.f, 0.f};
                b1 = (f32x4){0.f, 0.f, 0.f, 0.f};
                const short* eb = &s_ef[(t + 1) & 3][0] + lane * 8;
                #pragma unroll
                for (int kc = 0; kc < 4; ++kc) {
                    bf16x8 av = *(const bf16x8*)(eb + kc * 512);
                    bf16x8 aw = *(const bf16x8*)(eb + (kc + 4) * 512);
                    a0 = __builtin_amdgcn_mfma_f32_16x16x32_bf16(av, wA[kc], a0, 0, 0, 0);
                    b0 = __builtin_amdgcn_mfma_f32_16x16x32_bf16(av, wB[kc], b0, 0, 0, 0);
                    a1 = __builtin_amdgcn_mfma_f32_16x16x32_bf16(aw, wA[kc + 4], a1, 0, 0, 0);
                    b1 = __builtin_amdgcn_mfma_f32_16x16x32_bf16(aw, wB[kc + 4], b1, 0, 0, 0);
                }
            }
        } else {
            // ---- stage emb(t+3) into ring buf (t+3)&3 ----
            if (t + 3 < T_) {
                int tok = s_idx[(t + 3) * 16 + m16];
                if (TAB) {
                    gld16(embb + (size_t)tok * E_ + skoff,
                          &s_ef[(t + 3) & 3][(wave - 8) * 512]);
                } else {
                    const float* pr = embf + (size_t)tok * E_ + skoff;
                    float4 f0 = *(const float4*)pr;
                    float4 f1 = *(const float4*)(pr + 4);
                    u32x4 w;
                    w[0] = cvt_pk_bf16(f0.x, f0.y);
                    w[1] = cvt_pk_bf16(f0.z, f0.w);
                    w[2] = cvt_pk_bf16(f1.x, f1.y);
                    w[3] = cvt_pk_bf16(f1.z, f1.w);
                    *(u32x4*)(&s_ef[(t + 3) & 3][0] + sbase) = w;
                }
            }
        }
        if (TAB) {
            // newest stage load may stay in flight; oldest must retire
            asm volatile("s_waitcnt vmcnt(1) lgkmcnt(0)" ::: "memory");
            __builtin_amdgcn_s_barrier();
            __builtin_amdgcn_sched_barrier(0);
        } else {
            __syncthreads();
        }
    }

    if (wave < 8) {
        const int j = wave * 8 + u;
        out[(r0 + m0) * H_ + j]     = h0v;
        out[(r0 + m0 + 1) * H_ + j] = h1v;
    }
}

// ---------------------------------------------------------------------------
extern "C" void kernel_launch(void* const* d_in, const int* in_sizes, int n_in,
                              void* d_out, int out_size, void* d_ws, size_t ws_size,
                              hipStream_t stream) {
    const int*   x         = (const int*)d_in[0];
    const float* emb_table = (const float*)d_in[1];
    const float* W_ih      = (const float*)d_in[2];
    const float* W_hh      = (const float*)d_in[3];
    const float* b_ih      = (const float*)d_in[4];
    const float* b_hh      = (const float*)d_in[5];
    float*       out       = (float*)d_out;

    short* wih_frag = (short*)d_ws;               // 65536 shorts (128 KB)
    short* whh_g    = wih_frag + 65536;           // 16384 shorts (32 KB)
    float* bias_f   = (float*)(whh_g + 16384);    // 256 floats (1 KB)
    short* emb_bf   = (short*)(bias_f + 256);     // 8.192M shorts (16.4 MB)

    const size_t need = (size_t)(65536 + 16384) * 2 + 256 * 4
                      + (size_t)V_ * E_ * 2;
    const int tab = (ws_size >= need) ? 1 : 0;

    prep_kernel<<<tab ? 1024 : 64, 256, 0, stream>>>(
        W_ih, W_hh, b_ih, b_hh, emb_table,
        wih_frag, whh_g, bias_f,
        tab ? emb_bf : wih_frag, tab ? V_ * E_ : 0);

    if (tab) {
        lstm_f<1><<<B_ / 16, THREADS, 0, stream>>>(
            x, emb_table, emb_bf, wih_frag, whh_g, bias_f, out);
    } else {
        lstm_f<0><<<B_ / 16, THREADS, 0, stream>>>(
            x, emb_table, wih_frag, wih_frag, whh_g, bias_f, out);
    }
}

// Round 12
// 76.132 us; speedup vs baseline: 1.2340x; 1.2340x over previous
//
#include <hip/hip_runtime.h>
#include <math.h>

#define B_ 4096
#define T_ 64
#define E_ 256
#define H_ 64
#define V_ 32000
#define THREADS 1024

typedef __attribute__((ext_vector_type(8))) short bf16x8;
typedef __attribute__((ext_vector_type(4))) float f32x4;
typedef __attribute__((ext_vector_type(4))) unsigned int u32x4;

__device__ __forceinline__ short f2bf(float x) {
    unsigned u = __float_as_uint(x);
    return (short)((u + 0x7FFFu + ((u >> 16) & 1u)) >> 16);
}
__device__ __forceinline__ unsigned cvt_pk_bf16(float lo, float hi) {
    unsigned r;
    asm("v_cvt_pk_bf16_f32 %0, %1, %2" : "=v"(r) : "v"(lo), "v"(hi));
    return r;
}
__device__ __forceinline__ float exp2_raw(float x) {
    float r; asm("v_exp_f32 %0, %1" : "=v"(r) : "v"(x)); return r;
}
__device__ __forceinline__ float rcp_raw(float x) {
    float r; asm("v_rcp_f32 %0, %1" : "=v"(r) : "v"(x)); return r;
}
#define LOG2E 1.442695041f

__device__ __forceinline__ void gld16(const void* g, void* l) {
    __builtin_amdgcn_global_load_lds(
        (const __attribute__((address_space(1))) void*)g,
        (__attribute__((address_space(3))) void*)l, 16, 0, 0);
}

// ---------------------------------------------------------------------------
// Prep (wih_frag layout identical to R4-R11, verified):
//  wih_frag[((vv*2+tl)*8 + kc)*512 + lane*8 + jj]:
//    gate g = tl*128 + (lane&1)*64 + vv*8 + ((lane&15)>>1)
//    k      = kc*32 + (lane>>4)*8 + jj
//  whh_g: bf16 [g][k] row-major;  bias_f = b_ih + b_hh
//  emb_bf: whole table bf16 (RNE) for global_load_lds staging.
// ---------------------------------------------------------------------------
__global__ void prep_kernel(const float* __restrict__ W_ih,
                            const float* __restrict__ W_hh,
                            const float* __restrict__ b_ih,
                            const float* __restrict__ b_hh,
                            const float* __restrict__ emb_table,
                            short* __restrict__ wih_frag,
                            short* __restrict__ whh_g,
                            float* __restrict__ bias_f,
                            short* __restrict__ emb_bf,
                            int tabN) {
    int tid = blockIdx.x * blockDim.x + threadIdx.x;
    int stride = gridDim.x * blockDim.x;
    for (int i = tid; i < 65536; i += stride) {
        int jj = i & 7;
        int l  = (i >> 3) & 63;
        int kc = (i >> 9) & 7;
        int tl = (i >> 12) & 1;
        int vv = i >> 13;
        int uu = (l & 15) >> 1, pp = l & 1;
        int g = tl * 128 + pp * 64 + vv * 8 + uu;
        int k = kc * 32 + (l >> 4) * 8 + jj;
        wih_frag[i] = f2bf(W_ih[g * E_ + k]);
    }
    for (int i = tid; i < 256 * 64; i += stride) whh_g[i] = f2bf(W_hh[i]);
    for (int i = tid; i < 256; i += stride) bias_f[i] = b_ih[i] + b_hh[i];
    for (int i = tid; i < (tabN >> 2); i += stride) {
        float4 v = ((const float4*)emb_table)[i];
        uint2 w;
        w.x = cvt_pk_bf16(v.x, v.y);
        w.y = cvt_pk_bf16(v.z, v.w);
        ((uint2*)emb_bf)[i] = w;
    }
}

// ---------------------------------------------------------------------------
// R10 structure (75us, no spill) + counted-vmcnt barrier + setprio.
// grid 256 (1 block/CU), 1024 threads = 16 waves, pinned 4 waves/EU.
//  waves 0-7  (compute): wave w owns vv=w. W_ih (64 VGPR) + W_hh (16 VGPR)
//       register-resident; acc = 2 chains (pA, pB) -- split-K reverted, it
//       spilled (R11: +8 VGPR -> WRITE_SIZE 9.2 MB, -19us).
//  waves 8-15 (stage): wave 8+s stages chunk kc=s of emb(t+3) via ONE
//       global_load_lds dwordx4 (bf16 table), DISTANCE-3 prefetch, 4-ring.
// In-loop barrier (TAB): s_waitcnt vmcnt(1) lgkmcnt(0); s_barrier -- the
// fresh gather stays in flight across the barrier (a full step of slack);
// load for buf (t+3)&3 is consumed at step t+2, i.e. after 2 barriers ->
// retired by vmcnt(1) at the first one after next issue. R10's __syncthreads
// drained the fresh gather (~500-900cy L3 latency) inside EVERY step.
// setprio(1) wraps compute-wave MFMA regions (T5: wave-role split exists).
// Fragment LDS layout (zero-conflict): chunk (kc,lane) at kc*1024B + lane*16B.
// ---------------------------------------------------------------------------
template <int TAB>
__global__ __attribute__((amdgpu_flat_work_group_size(THREADS, THREADS),
                          amdgpu_waves_per_eu(4, 4)))
void lstm_f(const int* __restrict__ x,
            const float* __restrict__ embf,
            const short* __restrict__ embb,
            const short* __restrict__ wih_frag,
            const short* __restrict__ whh_g,
            const float* __restrict__ bias_f,
            float* __restrict__ out) {
    __shared__ __align__(16) short s_ef[4][4096];   // 4-ring emb, 8 KB each
    __shared__ __align__(16) short s_hf[2][1024];   // 2-ring h, 2 KB each
    __shared__ int s_idx[1024];                     // [t][m]

    const int tid  = threadIdx.x;
    const int lane = tid & 63;
    const int wave = tid >> 6;
    const int r0   = blockIdx.x * 16;

    s_idx[(tid & 63) * 16 + (tid >> 6)] = x[(r0 + (tid >> 6)) * T_ + (tid & 63)];
    ((int*)s_hf)[tid] = 0;

    const int p  = lane & 1;
    const int c4 = lane >> 4;
    const int u  = (lane & 15) >> 1;
    const float scl2 = p ? 1.0f : 2.0f;
    const float offB = p ? 0.0f : -1.0f;
    const float enB  = -LOG2E * scl2;
    const int m0 = c4 * 4 + p * 2;

    // ---- compute-wave setup ----
    bf16x8 wA[8], wB[8], qA0, qA1, qB0, qB1;
    float bA = 0.f, bB = 0.f;
    int hw_s = 0;
    if (wave < 8) {
        const short* wp = wih_frag + wave * 8192 + lane * 8;
        #pragma unroll
        for (int kc = 0; kc < 8; ++kc) {
            wA[kc] = *(const bf16x8*)(wp + kc * 512);
            wB[kc] = *(const bf16x8*)(wp + 4096 + kc * 512);
        }
        const int gA = p * 64 + wave * 8 + u;
        const short* qp = whh_g + gA * 64 + c4 * 8;
        qA0 = *(const bf16x8*)(qp);
        qA1 = *(const bf16x8*)(qp + 32);
        qB0 = *(const bf16x8*)(qp + 8192);
        qB1 = *(const bf16x8*)(qp + 8192 + 32);
        bA = bias_f[gA];
        bB = bias_f[gA + 128];
        hw_s = (wave >> 2) * 512 + (wave & 3) * 128
             + ((u & 1) ? (m0 + 1) * 8 + (u - 1) : m0 * 8 + u);
    }

    // ---- stage-wave mapping: wave 8+s owns chunk kc=s ----
    const int m16   = lane & 15;
    const int sbase = (wave - 8) * 512 + lane * 8;                 // shorts
    const int skoff = (wave - 8) * 32 + (lane >> 4) * 8;           // emb col

    __syncthreads();   // s_idx, h=0 visible

    if (wave >= 8) {
        // prologue: stage t=0,1,2 (0,1 must land; 2 may stay in flight)
        #pragma unroll
        for (int tt = 0; tt < 3; ++tt) {
            int tok = s_idx[tt * 16 + m16];
            if (TAB) {
                gld16(embb + (size_t)tok * E_ + skoff,
                      &s_ef[tt][(wave - 8) * 512]);
            } else {
                const float* pr = embf + (size_t)tok * E_ + skoff;
                float4 f0 = *(const float4*)pr;
                float4 f1 = *(const float4*)(pr + 4);
                u32x4 w;
                w[0] = cvt_pk_bf16(f0.x, f0.y);
                w[1] = cvt_pk_bf16(f0.z, f0.w);
                w[2] = cvt_pk_bf16(f1.x, f1.y);
                w[3] = cvt_pk_bf16(f1.z, f1.w);
                *(u32x4*)(&s_ef[tt][0] + sbase) = w;
            }
        }
    }
    if (TAB) {
        asm volatile("s_waitcnt vmcnt(1) lgkmcnt(0)" ::: "memory");
        __builtin_amdgcn_s_barrier();
        __builtin_amdgcn_sched_barrier(0);
    } else {
        __syncthreads();
    }

    // ---- compute prologue: pre-gates P(0) from buf0 ----
    f32x4 pA, pB;
    if (wave < 8) {
        pA = (f32x4){bA, bA, bA, bA};
        pB = (f32x4){bB, bB, bB, bB};
        const short* eb = &s_ef[0][0] + lane * 8;
        #pragma unroll
        for (int kc = 0; kc < 8; ++kc) {
            bf16x8 av = *(const bf16x8*)(eb + kc * 512);
            pA = __builtin_amdgcn_mfma_f32_16x16x32_bf16(av, wA[kc], pA, 0, 0, 0);
            pB = __builtin_amdgcn_mfma_f32_16x16x32_bf16(av, wB[kc], pB, 0, 0, 0);
        }
    }

    float c0 = 0.f, c1 = 0.f, h0v = 0.f, h1v = 0.f;

    #pragma unroll 4
    for (int t = 0; t < T_; ++t) {
        if (wave < 8) {
            // ---- R: G(t) = preG + h(t-1)*Whh ----
            const short* hb = &s_hf[t & 1][0] + lane * 8;
            bf16x8 hv0 = *(const bf16x8*)(hb);
            bf16x8 hv1 = *(const bf16x8*)(hb + 512);
            __builtin_amdgcn_s_setprio(1);
            pA = __builtin_amdgcn_mfma_f32_16x16x32_bf16(hv0, qA0, pA, 0, 0, 0);
            pA = __builtin_amdgcn_mfma_f32_16x16x32_bf16(hv1, qA1, pA, 0, 0, 0);
            pB = __builtin_amdgcn_mfma_f32_16x16x32_bf16(hv0, qB0, pB, 0, 0, 0);
            pB = __builtin_amdgcn_mfma_f32_16x16x32_bf16(hv1, qB1, pB, 0, 0, 0);
            __builtin_amdgcn_s_setprio(0);

            // ---- gates (raw v_exp/v_rcp; proven parity interleave) ----
            float sA[4], Bv[4];
            #pragma unroll
            for (int q = 0; q < 4; ++q) {
                sA[q] = rcp_raw(1.0f + exp2_raw(-LOG2E * pA[q]));        // sigm(i)|sigm(f)
                Bv[q] = rcp_raw(1.0f + exp2_raw(enB * pB[q])) * scl2 + offB; // tanh(g)|sigm(o)
            }
            float s1 = p ? sA[0] : sA[2] * Bv[2];
            float r1 = __shfl_xor(s1, 1);
            float s2 = p ? sA[1] : sA[3] * Bv[3];
            float r2 = __shfl_xor(s2, 1);
            float r3 = __shfl_xor(Bv[0], 1);
            float r4 = __shfl_xor(Bv[1], 1);
            float fc0 = p ? sA[2] : r1;
            float ic0 = p ? r1 : sA[0] * Bv[0];
            float oc0 = p ? Bv[2] : r3;
            float fc1 = p ? sA[3] : r2;
            float ic1 = p ? r2 : sA[1] * Bv[1];
            float oc1 = p ? Bv[3] : r4;
            c0 = fc0 * c0 + ic0;
            c1 = fc1 * c1 + ic1;
            h0v = oc0 * (1.0f - 2.0f * rcp_raw(1.0f + exp2_raw(2.0f * LOG2E * c0)));
            h1v = oc1 * (1.0f - 2.0f * rcp_raw(1.0f + exp2_raw(2.0f * LOG2E * c1)));

            // packed b32 h-write (column-pair via lane^2 exchange, cvt_pk)
            float snd = (u & 1) ? h0v : h1v;
            float rcv = __shfl_xor(snd, 2);
            unsigned hw = (u & 1) ? cvt_pk_bf16(rcv, h1v) : cvt_pk_bf16(h0v, rcv);
            *(unsigned*)(&s_hf[(t + 1) & 1][0] + hw_s) = hw;

            // ---- P: preG(t+1) = bias + emb(t+1)*Wih ----
            if (t < T_ - 1) {
                pA = (f32x4){bA, bA, bA, bA};
                pB = (f32x4){bB, bB, bB, bB};
                const short* eb = &s_ef[(t + 1) & 3][0] + lane * 8;
                __builtin_amdgcn_s_setprio(1);
                #pragma unroll
                for (int kc = 0; kc < 8; ++kc) {
                    bf16x8 av = *(const bf16x8*)(eb + kc * 512);
                    pA = __builtin_amdgcn_mfma_f32_16x16x32_bf16(av, wA[kc], pA, 0, 0, 0);
                    pB = __builtin_amdgcn_mfma_f32_16x16x32_bf16(av, wB[kc], pB, 0, 0, 0);
                }
                __builtin_amdgcn_s_setprio(0);
            }
        } else {
            // ---- stage emb(t+3) into ring buf (t+3)&3 ----
            if (t + 3 < T_) {
                int tok = s_idx[(t + 3) * 16 + m16];
                if (TAB) {
                    gld16(embb + (size_t)tok * E_ + skoff,
                          &s_ef[(t + 3) & 3][(wave - 8) * 512]);
                } else {
                    const float* pr = embf + (size_t)tok * E_ + skoff;
                    float4 f0 = *(const float4*)pr;
                    float4 f1 = *(const float4*)(pr + 4);
                    u32x4 w;
                    w[0] = cvt_pk_bf16(f0.x, f0.y);
                    w[1] = cvt_pk_bf16(f0.z, f0.w);
                    w[2] = cvt_pk_bf16(f1.x, f1.y);
                    w[3] = cvt_pk_bf16(f1.z, f1.w);
                    *(u32x4*)(&s_ef[(t + 3) & 3][0] + sbase) = w;
                }
            }
        }
        if (TAB) {
            // fresh gather stays in flight; previous one must retire
            asm volatile("s_waitcnt vmcnt(1) lgkmcnt(0)" ::: "memory");
            __builtin_amdgcn_s_barrier();
            __builtin_amdgcn_sched_barrier(0);
        } else {
            __syncthreads();
        }
    }

    if (wave < 8) {
        const int j = wave * 8 + u;
        out[(r0 + m0) * H_ + j]     = h0v;
        out[(r0 + m0 + 1) * H_ + j] = h1v;
    }
}

// ---------------------------------------------------------------------------
extern "C" void kernel_launch(void* const* d_in, const int* in_sizes, int n_in,
                              void* d_out, int out_size, void* d_ws, size_t ws_size,
                              hipStream_t stream) {
    const int*   x         = (const int*)d_in[0];
    const float* emb_table = (const float*)d_in[1];
    const float* W_ih      = (const float*)d_in[2];
    const float* W_hh      = (const float*)d_in[3];
    const float* b_ih      = (const float*)d_in[4];
    const float* b_hh      = (const float*)d_in[5];
    float*       out       = (float*)d_out;

    short* wih_frag = (short*)d_ws;               // 65536 shorts (128 KB)
    short* whh_g    = wih_frag + 65536;           // 16384 shorts (32 KB)
    float* bias_f   = (float*)(whh_g + 16384);    // 256 floats (1 KB)
    short* emb_bf   = (short*)(bias_f + 256);     // 8.192M shorts (16.4 MB)

    const size_t need = (size_t)(65536 + 16384) * 2 + 256 * 4
                      + (size_t)V_ * E_ * 2;
    const int tab = (ws_size >= need) ? 1 : 0;

    prep_kernel<<<tab ? 1024 : 64, 256, 0, stream>>>(
        W_ih, W_hh, b_ih, b_hh, emb_table,
        wih_frag, whh_g, bias_f,
        tab ? emb_bf : wih_frag, tab ? V_ * E_ : 0);

    if (tab) {
        lstm_f<1><<<B_ / 16, THREADS, 0, stream>>>(
            x, emb_table, emb_bf, wih_frag, whh_g, bias_f, out);
    } else {
        lstm_f<0><<<B_ / 16, THREADS, 0, stream>>>(
            x, emb_table, wih_frag, wih_frag, whh_g, bias_f, out);
    }
}

// Round 13
// 66.817 us; speedup vs baseline: 1.4060x; 1.1394x over previous
//
#include <hip/hip_runtime.h>
#include <math.h>

#define B_ 4096
#define T_ 64
#define E_ 256
#define H_ 64
#define V_ 32000
#define THREADS 1024

typedef __attribute__((ext_vector_type(8))) short bf16x8;
typedef __attribute__((ext_vector_type(4))) float f32x4;
typedef __attribute__((ext_vector_type(4))) unsigned int u32x4;

__device__ __forceinline__ short f2bf(float x) {
    unsigned u = __float_as_uint(x);
    return (short)((u + 0x7FFFu + ((u >> 16) & 1u)) >> 16);
}
__device__ __forceinline__ unsigned cvt_pk_bf16(float lo, float hi) {
    unsigned r;
    asm("v_cvt_pk_bf16_f32 %0, %1, %2" : "=v"(r) : "v"(lo), "v"(hi));
    return r;
}
__device__ __forceinline__ float exp2_raw(float x) {
    float r; asm("v_exp_f32 %0, %1" : "=v"(r) : "v"(x)); return r;
}
__device__ __forceinline__ float rcp_raw(float x) {
    float r; asm("v_rcp_f32 %0, %1" : "=v"(r) : "v"(x)); return r;
}
#define LOG2E 1.442695041f

// quad_perm DPP lane exchange (VALU, not DS): xor1 = [1,0,3,2] = 0xB1,
// xor2 = [2,3,0,1] = 0x4E. Exact replacement for __shfl_xor(x,1/2).
template <int CTRL>
__device__ __forceinline__ float dpp_f(float x) {
    return __int_as_float(
        __builtin_amdgcn_mov_dpp(__float_as_int(x), CTRL, 0xF, 0xF, true));
}

__device__ __forceinline__ void gld16(const void* g, void* l) {
    __builtin_amdgcn_global_load_lds(
        (const __attribute__((address_space(1))) void*)g,
        (__attribute__((address_space(3))) void*)l, 16, 0, 0);
}

// ---------------------------------------------------------------------------
// Prep (wih_frag layout identical to R4-R12, verified):
//  wih_frag[((vv*2+tl)*8 + kc)*512 + lane*8 + jj]:
//    gate g = tl*128 + (lane&1)*64 + vv*8 + ((lane&15)>>1)
//    k      = kc*32 + (lane>>4)*8 + jj
//  whh_g: bf16 [g][k] row-major;  bias_f = b_ih + b_hh
//  emb_bf: whole table bf16 (RNE) for global_load_lds staging.
// ---------------------------------------------------------------------------
__global__ void prep_kernel(const float* __restrict__ W_ih,
                            const float* __restrict__ W_hh,
                            const float* __restrict__ b_ih,
                            const float* __restrict__ b_hh,
                            const float* __restrict__ emb_table,
                            short* __restrict__ wih_frag,
                            short* __restrict__ whh_g,
                            float* __restrict__ bias_f,
                            short* __restrict__ emb_bf,
                            int tabN) {
    int tid = blockIdx.x * blockDim.x + threadIdx.x;
    int stride = gridDim.x * blockDim.x;
    for (int i = tid; i < 65536; i += stride) {
        int jj = i & 7;
        int l  = (i >> 3) & 63;
        int kc = (i >> 9) & 7;
        int tl = (i >> 12) & 1;
        int vv = i >> 13;
        int uu = (l & 15) >> 1, pp = l & 1;
        int g = tl * 128 + pp * 64 + vv * 8 + uu;
        int k = kc * 32 + (l >> 4) * 8 + jj;
        wih_frag[i] = f2bf(W_ih[g * E_ + k]);
    }
    for (int i = tid; i < 256 * 64; i += stride) whh_g[i] = f2bf(W_hh[i]);
    for (int i = tid; i < 256; i += stride) bias_f[i] = b_ih[i] + b_hh[i];
    for (int i = tid; i < (tabN >> 2); i += stride) {
        float4 v = ((const float4*)emb_table)[i];
        uint2 w;
        w.x = cvt_pk_bf16(v.x, v.y);
        w.y = cvt_pk_bf16(v.z, v.w);
        ((uint2*)emb_bf)[i] = w;
    }
}

// ---------------------------------------------------------------------------
// R12 structure + DPP shuffles + ANTI-PHASE compute groups.
// grid 256 (1 block/CU), 1024 threads = 16 waves, pinned 4 waves/EU.
//  waves 0-3 (group A): R -> gates -> h-write -> P(t+1)
//  waves 4-7 (group B): R -> stash G to private LDS -> P(t+1) -> unstash ->
//       gates -> h-write   (sched_barrier(0) pins the order; stash avoids
//       +8 VGPR live-through-P, which spilled in R11)
//  Wave w and w+4 share SIMD w&3 -> one wave is in MFMA-heavy P while the
//  other is in trans-heavy gates: pipes interleave instead of alternating.
//  waves 8-15 (stage): wave 8+s stages chunk kc=s of emb(t+3) via ONE
//       global_load_lds dwordx4 (bf16 table), distance-3 prefetch, 4-ring,
//       counted-vmcnt barrier (vmcnt(1)).
// All lane exchanges are quad_perm DPP (removes 40 DS-ops/CU/step from the
// contended LDS pipe + ~240cy of DS latency from the gate serial chain).
// Fragment LDS layout (zero-conflict): chunk (kc,lane) at kc*1024B + lane*16B.
// ---------------------------------------------------------------------------
template <int TAB>
__global__ __attribute__((amdgpu_flat_work_group_size(THREADS, THREADS),
                          amdgpu_waves_per_eu(4, 4)))
void lstm_f(const int* __restrict__ x,
            const float* __restrict__ embf,
            const short* __restrict__ embb,
            const short* __restrict__ wih_frag,
            const short* __restrict__ whh_g,
            const float* __restrict__ bias_f,
            float* __restrict__ out) {
    __shared__ __align__(16) short s_ef[4][4096];   // 4-ring emb, 8 KB each
    __shared__ __align__(16) short s_hf[2][1024];   // 2-ring h, 2 KB each
    __shared__ __align__(16) float s_gst[4 * 512];  // group-B G stash, 8 KB
    __shared__ int s_idx[1024];                     // [t][m]

    const int tid  = threadIdx.x;
    const int lane = tid & 63;
    const int wave = tid >> 6;
    const int r0   = blockIdx.x * 16;

    s_idx[(tid & 63) * 16 + (tid >> 6)] = x[(r0 + (tid >> 6)) * T_ + (tid & 63)];
    ((int*)s_hf)[tid] = 0;

    const int p  = lane & 1;
    const int c4 = lane >> 4;
    const int u  = (lane & 15) >> 1;
    const float scl2 = p ? 1.0f : 2.0f;
    const float offB = p ? 0.0f : -1.0f;
    const float enB  = -LOG2E * scl2;
    const int m0 = c4 * 4 + p * 2;

    // ---- compute-wave setup ----
    bf16x8 wA[8], wB[8], qA0, qA1, qB0, qB1;
    float bA = 0.f, bB = 0.f;
    int hw_s = 0;
    if (wave < 8) {
        const short* wp = wih_frag + wave * 8192 + lane * 8;
        #pragma unroll
        for (int kc = 0; kc < 8; ++kc) {
            wA[kc] = *(const bf16x8*)(wp + kc * 512);
            wB[kc] = *(const bf16x8*)(wp + 4096 + kc * 512);
        }
        const int gA = p * 64 + wave * 8 + u;
        const short* qp = whh_g + gA * 64 + c4 * 8;
        qA0 = *(const bf16x8*)(qp);
        qA1 = *(const bf16x8*)(qp + 32);
        qB0 = *(const bf16x8*)(qp + 8192);
        qB1 = *(const bf16x8*)(qp + 8192 + 32);
        bA = bias_f[gA];
        bB = bias_f[gA + 128];
        hw_s = (wave >> 2) * 512 + (wave & 3) * 128
             + ((u & 1) ? (m0 + 1) * 8 + (u - 1) : m0 * 8 + u);
    }

    // ---- stage-wave mapping: wave 8+s owns chunk kc=s ----
    const int m16   = lane & 15;
    const int sbase = (wave - 8) * 512 + lane * 8;                 // shorts
    const int skoff = (wave - 8) * 32 + (lane >> 4) * 8;           // emb col

    __syncthreads();   // s_idx, h=0 visible

    if (wave >= 8) {
        // prologue: stage t=0,1,2 (0,1 must land; 2 may stay in flight)
        #pragma unroll
        for (int tt = 0; tt < 3; ++tt) {
            int tok = s_idx[tt * 16 + m16];
            if (TAB) {
                gld16(embb + (size_t)tok * E_ + skoff,
                      &s_ef[tt][(wave - 8) * 512]);
            } else {
                const float* pr = embf + (size_t)tok * E_ + skoff;
                float4 f0 = *(const float4*)pr;
                float4 f1 = *(const float4*)(pr + 4);
                u32x4 w;
                w[0] = cvt_pk_bf16(f0.x, f0.y);
                w[1] = cvt_pk_bf16(f0.z, f0.w);
                w[2] = cvt_pk_bf16(f1.x, f1.y);
                w[3] = cvt_pk_bf16(f1.z, f1.w);
                *(u32x4*)(&s_ef[tt][0] + sbase) = w;
            }
        }
    }
    if (TAB) {
        asm volatile("s_waitcnt vmcnt(1) lgkmcnt(0)" ::: "memory");
        __builtin_amdgcn_s_barrier();
        __builtin_amdgcn_sched_barrier(0);
    } else {
        __syncthreads();
    }

    float c0 = 0.f, c1 = 0.f, h0v = 0.f, h1v = 0.f;
    f32x4 pA, pB;
    float* sg = s_gst + (wave & 3) * 512 + lane * 8;   // group-B stash slot

    // ---- compute prologue: pre-gates P(0) from buf0 ----
    if (wave < 8) {
        pA = (f32x4){bA, bA, bA, bA};
        pB = (f32x4){bB, bB, bB, bB};
        const short* eb = &s_ef[0][0] + lane * 8;
        #pragma unroll
        for (int kc = 0; kc < 8; ++kc) {
            bf16x8 av = *(const bf16x8*)(eb + kc * 512);
            pA = __builtin_amdgcn_mfma_f32_16x16x32_bf16(av, wA[kc], pA, 0, 0, 0);
            pB = __builtin_amdgcn_mfma_f32_16x16x32_bf16(av, wB[kc], pB, 0, 0, 0);
        }
    }

    // gates: full gate math from pre-activations GA/GB, h-write for step t
    auto gates_phase = [&](f32x4 GA, f32x4 GB, int t) {
        float sA[4], Bv[4];
        #pragma unroll
        for (int q = 0; q < 4; ++q) {
            sA[q] = rcp_raw(1.0f + exp2_raw(-LOG2E * GA[q]));          // sigm(i)|sigm(f)
            Bv[q] = rcp_raw(1.0f + exp2_raw(enB * GB[q])) * scl2 + offB; // tanh(g)|sigm(o)
        }
        float s1 = p ? sA[0] : sA[2] * Bv[2];
        float r1 = dpp_f<0xB1>(s1);
        float s2 = p ? sA[1] : sA[3] * Bv[3];
        float r2 = dpp_f<0xB1>(s2);
        float r3 = dpp_f<0xB1>(Bv[0]);
        float r4 = dpp_f<0xB1>(Bv[1]);
        float fc0 = p ? sA[2] : r1;
        float ic0 = p ? r1 : sA[0] * Bv[0];
        float oc0 = p ? Bv[2] : r3;
        float fc1 = p ? sA[3] : r2;
        float ic1 = p ? r2 : sA[1] * Bv[1];
        float oc1 = p ? Bv[3] : r4;
        c0 = fc0 * c0 + ic0;
        c1 = fc1 * c1 + ic1;
        h0v = oc0 * (1.0f - 2.0f * rcp_raw(1.0f + exp2_raw(2.0f * LOG2E * c0)));
        h1v = oc1 * (1.0f - 2.0f * rcp_raw(1.0f + exp2_raw(2.0f * LOG2E * c1)));
        float snd = (u & 1) ? h0v : h1v;
        float rcv = dpp_f<0x4E>(snd);
        unsigned hw = (u & 1) ? cvt_pk_bf16(rcv, h1v) : cvt_pk_bf16(h0v, rcv);
        *(unsigned*)(&s_hf[(t + 1) & 1][0] + hw_s) = hw;
    };

    auto p_phase = [&](int t) {   // preG(t+1) into pA/pB
        pA = (f32x4){bA, bA, bA, bA};
        pB = (f32x4){bB, bB, bB, bB};
        const short* eb = &s_ef[(t + 1) & 3][0] + lane * 8;
        __builtin_amdgcn_s_setprio(1);
        #pragma unroll
        for (int kc = 0; kc < 8; ++kc) {
            bf16x8 av = *(const bf16x8*)(eb + kc * 512);
            pA = __builtin_amdgcn_mfma_f32_16x16x32_bf16(av, wA[kc], pA, 0, 0, 0);
            pB = __builtin_amdgcn_mfma_f32_16x16x32_bf16(av, wB[kc], pB, 0, 0, 0);
        }
        __builtin_amdgcn_s_setprio(0);
    };

    #pragma unroll 4
    for (int t = 0; t < T_; ++t) {
        if (wave < 8) {
            // ---- R: G(t) = preG + h(t-1)*Whh ----
            const short* hb = &s_hf[t & 1][0] + lane * 8;
            bf16x8 hv0 = *(const bf16x8*)(hb);
            bf16x8 hv1 = *(const bf16x8*)(hb + 512);
            __builtin_amdgcn_s_setprio(1);
            pA = __builtin_amdgcn_mfma_f32_16x16x32_bf16(hv0, qA0, pA, 0, 0, 0);
            pA = __builtin_amdgcn_mfma_f32_16x16x32_bf16(hv1, qA1, pA, 0, 0, 0);
            pB = __builtin_amdgcn_mfma_f32_16x16x32_bf16(hv0, qB0, pB, 0, 0, 0);
            pB = __builtin_amdgcn_mfma_f32_16x16x32_bf16(hv1, qB1, pB, 0, 0, 0);
            __builtin_amdgcn_s_setprio(0);

            if (wave < 4) {
                // ---- group A: gates first, then P ----
                gates_phase(pA, pB, t);
                if (t < T_ - 1) p_phase(t);
            } else {
                // ---- group B: stash G, P first, then gates ----
                *(f32x4*)sg       = pA;
                *(f32x4*)(sg + 4) = pB;
                __builtin_amdgcn_sched_barrier(0);
                if (t < T_ - 1) p_phase(t);
                __builtin_amdgcn_sched_barrier(0);
                f32x4 GA = *(const f32x4*)sg;
                f32x4 GB = *(const f32x4*)(sg + 4);
                gates_phase(GA, GB, t);
            }
        } else {
            // ---- stage emb(t+3) into ring buf (t+3)&3 ----
            if (t + 3 < T_) {
                int tok = s_idx[(t + 3) * 16 + m16];
                if (TAB) {
                    gld16(embb + (size_t)tok * E_ + skoff,
                          &s_ef[(t + 3) & 3][(wave - 8) * 512]);
                } else {
                    const float* pr = embf + (size_t)tok * E_ + skoff;
                    float4 f0 = *(const float4*)pr;
                    float4 f1 = *(const float4*)(pr + 4);
                    u32x4 w;
                    w[0] = cvt_pk_bf16(f0.x, f0.y);
                    w[1] = cvt_pk_bf16(f0.z, f0.w);
                    w[2] = cvt_pk_bf16(f1.x, f1.y);
                    w[3] = cvt_pk_bf16(f1.z, f1.w);
                    *(u32x4*)(&s_ef[(t + 3) & 3][0] + sbase) = w;
                }
            }
        }
        if (TAB) {
            asm volatile("s_waitcnt vmcnt(1) lgkmcnt(0)" ::: "memory");
            __builtin_amdgcn_s_barrier();
            __builtin_amdgcn_sched_barrier(0);
        } else {
            __syncthreads();
        }
    }

    if (wave < 8) {
        const int j = wave * 8 + u;
        out[(r0 + m0) * H_ + j]     = h0v;
        out[(r0 + m0 + 1) * H_ + j] = h1v;
    }
}

// ---------------------------------------------------------------------------
extern "C" void kernel_launch(void* const* d_in, const int* in_sizes, int n_in,
                              void* d_out, int out_size, void* d_ws, size_t ws_size,
                              hipStream_t stream) {
    const int*   x         = (const int*)d_in[0];
    const float* emb_table = (const float*)d_in[1];
    const float* W_ih      = (const float*)d_in[2];
    const float* W_hh      = (const float*)d_in[3];
    const float* b_ih      = (const float*)d_in[4];
    const float* b_hh      = (const float*)d_in[5];
    float*       out       = (float*)d_out;

    short* wih_frag = (short*)d_ws;               // 65536 shorts (128 KB)
    short* whh_g    = wih_frag + 65536;           // 16384 shorts (32 KB)
    float* bias_f   = (float*)(whh_g + 16384);    // 256 floats (1 KB)
    short* emb_bf   = (short*)(bias_f + 256);     // 8.192M shorts (16.4 MB)

    const size_t need = (size_t)(65536 + 16384) * 2 + 256 * 4
                      + (size_t)V_ * E_ * 2;
    const int tab = (ws_size >= need) ? 1 : 0;

    prep_kernel<<<tab ? 1024 : 64, 256, 0, stream>>>(
        W_ih, W_hh, b_ih, b_hh, emb_table,
        wih_frag, whh_g, bias_f,
        tab ? emb_bf : wih_frag, tab ? V_ * E_ : 0);

    if (tab) {
        lstm_f<1><<<B_ / 16, THREADS, 0, stream>>>(
            x, emb_table, emb_bf, wih_frag, whh_g, bias_f, out);
    } else {
        lstm_f<0><<<B_ / 16, THREADS, 0, stream>>>(
            x, emb_table, wih_frag, wih_frag, whh_g, bias_f, out);
    }
}